// Round 1
// baseline (1817.568 us; speedup 1.0000x reference)
//
#include <hip/hip_runtime.h>

// LSTM rollout: B=1024, S=128, H=256, given_len=32.
// Persistent cooperative kernel: 256 blocks x 256 threads (1 block/CU).
// 64 groups of 4 blocks; group handles 16 batches; member r owns hidden
// units [r*64, r*64+64) => gate rows {q*256 + r*64 + u}. W_hh slice lives
// in MFMA B-fragment registers (fp16). Per step: MFMA gates -> cell update
// -> publish h-slice (global, double-buffered) -> flag sync -> refetch full
// h as A-fragments + compute y = h@W_out^T + b_out (redundantly per member).

#define NBLK 256
#define NTHR 256
#define SEQ 128
#define HID 256
#define GLEN 32

typedef _Float16 f16;
typedef _Float16 half8 __attribute__((ext_vector_type(8)));
typedef float floatx4 __attribute__((ext_vector_type(4)));

__device__ __forceinline__ float fast_exp2(float x) { return __builtin_amdgcn_exp2f(x); }
__device__ __forceinline__ float fast_rcp(float x) { return __builtin_amdgcn_rcpf(x); }
__device__ __forceinline__ float sigmoid_f(float x) {
  return fast_rcp(1.0f + fast_exp2(-1.44269504088896341f * x));
}
__device__ __forceinline__ float tanh_f(float x) {
  // tanh(x) = 1 - 2/(exp2(2x*log2e)+1); saturates correctly for |x| large.
  float e = fast_exp2(2.88539008177792681f * x);
  return 1.0f - 2.0f * fast_rcp(e + 1.0f);
}

__global__ __launch_bounds__(NTHR, 1)
void lstm_rollout_kernel(const float* __restrict__ prefix,
                         const float* __restrict__ W_ih,
                         const float* __restrict__ W_hh,
                         const float* __restrict__ b_ih,
                         const float* __restrict__ b_hh,
                         const float* __restrict__ W_out,
                         const float* __restrict__ b_out,
                         float* __restrict__ out,
                         unsigned int* __restrict__ flags,  // [64][16] u32 (64B/group pad)
                         f16* __restrict__ exch)            // [2][64][4][16][64] f16
{
  const int tid  = threadIdx.x;
  const int lane = tid & 63;
  const int wv   = tid >> 6;       // wave 0..3 -> owns unit sub-slice wv*16..wv*16+15
  const int n15  = lane & 15;      // MFMA col (N) / A row (M) index
  const int l4   = lane >> 4;      // 0..3

  // Group/member with XCD affinity under round-robin blockIdx%8 mapping
  // (perf heuristic only; correctness is scope-safe either way).
  const int blk = blockIdx.x;
  const int xcd = blk & 7;
  const int ii  = blk >> 3;        // 0..31
  const int g   = xcd * 8 + (ii >> 2);   // 0..63
  const int r   = ii & 3;                // member 0..3
  const int bbase = g * 16;

  __shared__ float wout_pad[4][72];  // padded: bank = (q*72+j)%32 distinct per q
  __shared__ float xbuf[16];

  if (tid < HID) wout_pad[tid >> 6][tid & 63] = W_out[tid];
  const float bout = b_out[0];

  // Per-lane owned gate rows: row(q) = q*256 + r*64 + wv*16 + n15.
  float biasq[4], wihq[4];
  half8 wfrag[4][8];  // [gate q][k-step t]: lane holds W_hh[row(q)][32t + l4*8 + j]
#pragma unroll
  for (int q = 0; q < 4; ++q) {
    const int row = q * 256 + r * 64 + wv * 16 + n15;
    biasq[q] = b_ih[row] + b_hh[row];
    wihq[q]  = W_ih[row];
    const float* wr = W_hh + row * HID;
#pragma unroll
    for (int t = 0; t < 8; ++t) {
      const float* src = wr + t * 32 + l4 * 8;
      half8 hv;
#pragma unroll
      for (int j = 0; j < 8; ++j) hv[j] = (f16)src[j];
      wfrag[q][t] = hv;
    }
  }

  // h(0) = 0 A-fragments; c(0) = 0.
  half8 afrag[8];
#pragma unroll
  for (int t = 0; t < 8; ++t)
#pragma unroll
    for (int j = 0; j < 8; ++j) afrag[t][j] = (f16)0.0f;
  float cst[4] = {0.f, 0.f, 0.f, 0.f};

  // x(0) = prefix[:,0]; copy prefix part of output (positions 0..31).
  if (tid < 16) xbuf[tid] = prefix[(bbase + tid) * SEQ + 0];
  if (r == 0) {
    for (int e = tid; e < 16 * GLEN; e += NTHR) {
      const int bi = e >> 5, ss = e & 31;
      out[(bbase + bi) * SEQ + ss] = prefix[(bbase + bi) * SEQ + ss];
    }
  }
  __syncthreads();

  const int BUFH = 64 * 4096;  // halves per exchange buffer
  unsigned int* const myflags = flags + g * 16;

  for (int s = 0; s < SEQ; ++s) {
    // ---- Phase A: gates = h(s) @ W_hh_slice^T (fp32 accum) ----
    floatx4 acc[4];
#pragma unroll
    for (int q = 0; q < 4; ++q) acc[q] = (floatx4){0.f, 0.f, 0.f, 0.f};
#pragma unroll
    for (int t = 0; t < 8; ++t) {
#pragma unroll
      for (int q = 0; q < 4; ++q)
        acc[q] = __builtin_amdgcn_mfma_f32_16x16x32_f16(afrag[t], wfrag[q][t], acc[q], 0, 0, 0);
    }

    // ---- Phase B: cell update for (4 batches) x (1 unit) per lane ----
    // acc[q][reg]: batch m = l4*4+reg, unit u = r*64 + wv*16 + n15, gate q.
    f16 hnew[4];
#pragma unroll
    for (int reg = 0; reg < 4; ++reg) {
      const float xv = xbuf[l4 * 4 + reg];
      const float gi = acc[0][reg] + xv * wihq[0] + biasq[0];
      const float gf = acc[1][reg] + xv * wihq[1] + biasq[1];
      const float gg = acc[2][reg] + xv * wihq[2] + biasq[2];
      const float go = acc[3][reg] + xv * wihq[3] + biasq[3];
      const float cn = sigmoid_f(gf) * cst[reg] + sigmoid_f(gi) * tanh_f(gg);
      cst[reg] = cn;
      hnew[reg] = (f16)(sigmoid_f(go) * tanh_f(cn));
    }

    // ---- Phase C: publish own h(s+1) slice; release flag ----
    f16* const wbuf = exch + ((s + 1) & 1) * BUFH + g * 4096 + r * 1024;
#pragma unroll
    for (int reg = 0; reg < 4; ++reg) {
      const int m = l4 * 4 + reg;
      wbuf[m * 64 + wv * 16 + n15] = hnew[reg];
    }
    __syncthreads();  // drains all waves' stores (vmcnt 0) before flag
    if (tid == 0) {
      __threadfence();
      __hip_atomic_store(&myflags[r], (unsigned)(s + 1), __ATOMIC_RELEASE,
                         __HIP_MEMORY_SCOPE_AGENT);
    }

    // ---- Phase D: wait for all 4 members of the group ----
    if (tid < 4) {
      int guard = 0;
      while (__hip_atomic_load(&myflags[tid], __ATOMIC_ACQUIRE,
                               __HIP_MEMORY_SCOPE_AGENT) < (unsigned)(s + 1)) {
        __builtin_amdgcn_s_sleep(1);
        if (++guard > 2000000) break;  // turn a deadlock bug into wrong-but-finite
      }
    }
    __syncthreads();

    // ---- Phase E: fetch full h(s+1) as next A-fragments; y; next x ----
    const f16* const gbuf = exch + ((s + 1) & 1) * BUFH + g * 4096;
#pragma unroll
    for (int t = 0; t < 8; ++t) {
      const int k = t * 32 + l4 * 8;  // global unit index range [k, k+8)
      afrag[t] = *(const half8*)(gbuf + (k >> 6) * 1024 + n15 * 64 + (k & 63));
    }

    if (wv == 0) {
      // y[m] = dot(h(s+1)[m,:], W_out) + b_out ; lane = m*4 + quarter
      const int m0 = lane >> 2, q4 = lane & 3;
      const f16* const hrow = gbuf + q4 * 1024 + m0 * 64;
      float sum = 0.f;
#pragma unroll
      for (int jj = 0; jj < 8; ++jj) {
        const half8 hv = *(const half8*)(hrow + jj * 8);
#pragma unroll
        for (int e = 0; e < 8; ++e) sum += (float)hv[e] * wout_pad[q4][jj * 8 + e];
      }
      sum += __shfl_xor(sum, 1);
      sum += __shfl_xor(sum, 2);
      const float y = sum + bout;

      const int sn = s + 1;
      if (sn < SEQ) {
        if (sn <= GLEN) {  // warm-up x, incl. the repeated prefix[31] at sn==32
          if (lane < 16) {
            const int idx = (sn == GLEN) ? (GLEN - 1) : sn;
            xbuf[lane] = prefix[(bbase + lane) * SEQ + idx];
          }
        } else if (q4 == 0) {
          xbuf[m0] = y;  // autoregressive feedback
        }
      }
      if (s >= GLEN && r == 0 && q4 == 0) out[(bbase + m0) * SEQ + s] = y;
    }
    __syncthreads();
  }
}

extern "C" void kernel_launch(void* const* d_in, const int* in_sizes, int n_in,
                              void* d_out, int out_size, void* d_ws, size_t ws_size,
                              hipStream_t stream) {
  const float* prefix = (const float*)d_in[0];
  const float* W_ih   = (const float*)d_in[1];
  const float* W_hh   = (const float*)d_in[2];
  const float* b_ih   = (const float*)d_in[3];
  const float* b_hh   = (const float*)d_in[4];
  const float* W_out  = (const float*)d_in[5];
  const float* b_out  = (const float*)d_in[6];
  float* out = (float*)d_out;

  // ws layout: [0,4096) flags (zeroed each launch), [4096, 4096+1MB) exchange.
  unsigned int* flags = (unsigned int*)d_ws;
  f16* exch = (f16*)((char*)d_ws + 4096);
  hipMemsetAsync(d_ws, 0, 4096, stream);

  void* args[] = {(void*)&prefix, (void*)&W_ih, (void*)&W_hh, (void*)&b_ih,
                  (void*)&b_hh, (void*)&W_out, (void*)&b_out, (void*)&out,
                  (void*)&flags, (void*)&exch};
  hipError_t err = hipLaunchCooperativeKernel(
      reinterpret_cast<void*>(lstm_rollout_kernel), dim3(NBLK), dim3(NTHR),
      args, 0, stream);
  if (err != hipSuccess) {
    // Fallback: 256 blocks on 256 CUs are co-resident on an idle device.
    lstm_rollout_kernel<<<dim3(NBLK), dim3(NTHR), 0, stream>>>(
        prefix, W_ih, W_hh, b_ih, b_hh, W_out, b_out, out, flags, exch);
  }
}

// Round 2
// 704.888 us; speedup vs baseline: 2.5785x; 2.5785x over previous
//
#include <hip/hip_runtime.h>

// LSTM rollout: B=1024, S=128, H=256, given_len=32.
// Zero-communication design: 256 blocks x 256 threads, 1 block/CU, 4 batches
// per block. Full W_hh (fp16) resident per CU, split 3 ways:
//   - 320 KB in VGPRs (80 B-fragments/lane, tk=0..4)
//   - 128 KB in LDS   (tk=5,6), streamed via ds_read_b128 each step
//   -  64 KB in global(tk=7), L2-resident, streamed each step
// A prep kernel re-layouts W_hh (fp32 row-major) into fp16 MFMA B-fragments
// in d_ws every launch. No inter-block sync at all; 2 barriers/step.

#define SEQ 128
#define HID 256
#define GLEN 32
#define NB  256
#define NT  256

typedef _Float16 f16;
typedef _Float16 half8 __attribute__((ext_vector_type(8)));
typedef float floatx4 __attribute__((ext_vector_type(4)));
typedef float floatx2 __attribute__((ext_vector_type(2)));

// d_ws byte offsets
#define OFF_REG   0u            // 320 KB: 320 reg-fragments
#define OFF_LDSF  (320u << 10)  // 128 KB: 128 LDS-fragments
#define OFF_L2F   (448u << 10)  //  64 KB:  64 L2-fragments
#define OFF_COMBO (512u << 10)  //   8 KB: per-row {W_ih, b_ih+b_hh}

__device__ __forceinline__ float sigf(float x) {
  return __builtin_amdgcn_rcpf(1.0f + __builtin_amdgcn_exp2f(-1.44269504088896341f * x));
}
__device__ __forceinline__ float tanhf_(float x) {
  float e = __builtin_amdgcn_exp2f(2.88539008177792681f * x);
  return 1.0f - 2.0f * __builtin_amdgcn_rcpf(e + 1.0f);
}

// ---------------- prep: W_hh fp32 -> fp16 fragments, combo table ----------
__global__ void lstm_prep(const float* __restrict__ W_ih,
                          const float* __restrict__ W_hh,
                          const float* __restrict__ b_ih,
                          const float* __restrict__ b_hh,
                          char* __restrict__ ws)
{
  const int blk = blockIdx.x, tid = threadIdx.x;
  if (blk < 128) {
    const int gid = blk * 256 + tid;
    const int F = gid >> 6, lane = gid & 63;
    int tn, tk; size_t dst;
    if (F < 320) {               // reg fragments: F = w*80 + U*20 + q*5 + tk
      int w = F / 80, rem = F % 80, U = rem / 20, r2 = rem % 20, q = r2 / 5;
      tk = r2 % 5;
      tn = q * 16 + U * 4 + w;
      dst = OFF_REG + (size_t)F * 1024;
    } else if (F < 448) {        // LDS fragments: tk = 5,6
      int F2 = F - 320; tn = F2 >> 1; tk = 5 + (F2 & 1);
      dst = OFF_LDSF + (size_t)F2 * 1024;
    } else {                     // L2 fragments: tk = 7
      int F3 = F - 448; tn = F3; tk = 7;
      dst = OFF_L2F + (size_t)F3 * 1024;
    }
    const int row = tn * 16 + (lane & 15);
    const int k0  = tk * 32 + (lane >> 4) * 8;
    const float* src = W_hh + row * HID + k0;
    half8 hv;
#pragma unroll
    for (int j = 0; j < 8; ++j) hv[j] = (f16)src[j];
    *(half8*)(ws + dst + lane * 16) = hv;
  } else {
    for (int r = tid; r < 4 * HID; r += 256) {
      floatx2 cw; cw[0] = W_ih[r]; cw[1] = b_ih[r] + b_hh[r];
      *(floatx2*)(ws + OFF_COMBO + (size_t)r * 8) = cw;
    }
  }
}

// ---------------- main: persistent per-CU LSTM ----------------------------
__global__ __launch_bounds__(NT, 1)
void lstm_main(const float* __restrict__ prefix,
               const float* __restrict__ W_out,
               const float* __restrict__ b_out,
               const char* __restrict__ ws,
               float* __restrict__ out)
{
  __shared__ __align__(16) char fragL[128 * 1024];  // tk=5,6 fragments
  __shared__ __align__(16) char hbuf[8192];         // h fp16 [16m][256u] XOR-swz
  __shared__ __align__(16) floatx2 comboL[4 * HID]; // {W_ih, bias} per row
  __shared__ float woutL[HID];
  __shared__ float xcur[4];

  const int tid  = threadIdx.x;
  const int lane = tid & 63;
  const int wv   = tid >> 6;
  const int m15  = lane & 15;
  const int hi4  = lane >> 4;
  const int bbase = blockIdx.x * 4;

  // ---- init: stage LDS fragments, tables, zero h ----
  for (int i = tid; i < 8192; i += NT)
    *(int4*)(fragL + (size_t)i * 16) = *(const int4*)(ws + OFF_LDSF + (size_t)i * 16);
  for (int i = tid; i < 4 * HID; i += NT)
    comboL[i] = *(const floatx2*)(ws + OFF_COMBO + (size_t)i * 8);
  if (tid < HID) woutL[tid] = W_out[tid];
  { int4 z = {0, 0, 0, 0}; *(int4*)(hbuf + tid * 32) = z; }
  if (tid < 4) xcur[tid] = prefix[(bbase + tid) * SEQ + 0];
  if (tid < 128) {
    int b = tid >> 5, p = tid & 31;
    out[(bbase + b) * SEQ + p] = prefix[(bbase + b) * SEQ + p];
  }
  const float bout = b_out[0];

  // register-resident weight fragments: wreg[U][q][tk], tk=0..4
  half8 wreg[4][4][5];
  {
    const char* rbase = ws + OFF_REG + (size_t)wv * (80 * 1024) + (size_t)lane * 16;
#pragma unroll
    for (int U = 0; U < 4; ++U)
#pragma unroll
      for (int q = 0; q < 4; ++q)
#pragma unroll
        for (int tk = 0; tk < 5; ++tk)
          wreg[U][q][tk] = *(const half8*)(rbase + ((U * 4 + q) * 5 + tk) * 1024);
  }

  // prefix feed values for the y-phase shuffle (used by wave 0 only)
  float pl0 = 0.f, pl1 = 0.f;
  {
    int b = hi4 & 3;
    pl0 = prefix[(bbase + b) * SEQ + m15];
    pl1 = prefix[(bbase + b) * SEQ + 16 + m15];
  }

  float cst[4][4];
#pragma unroll
  for (int U = 0; U < 4; ++U)
#pragma unroll
    for (int r = 0; r < 4; ++r) cst[U][r] = 0.f;

  __syncthreads();

  const char* l2b = ws + OFF_L2F + (size_t)lane * 16;

  for (int s = 0; s < SEQ; ++s) {
    // ---- 1. A-fragments of h^s (all waves identical) ----
    half8 afrag[8];
#pragma unroll
    for (int tk = 0; tk < 8; ++tk) {
      int byte = (m15 * 512 + tk * 64 + hi4 * 16) ^ ((m15 & 7) << 4);
      afrag[tk] = *(const half8*)(hbuf + byte);
    }
    __syncthreads();  // B1: A-reads done -> hbuf/xcur writable

    float xv[4];
#pragma unroll
    for (int r = 0; r < 4; ++r) xv[r] = xcur[r];

    // ---- 3. per unit-block: gates MFMA, cell update, h write ----
#pragma unroll
    for (int U = 0; U < 4; ++U) {
      const int Ug = U * 4 + wv;      // global unit-block 0..15
      half8 bg[4], bl0[4], bl1[4];
#pragma unroll
      for (int q = 0; q < 4; ++q) {   // issue streamed B loads early
        const int tn = q * 16 + Ug;
        bg[q]  = *(const half8*)(l2b + (size_t)tn * 1024);
        bl0[q] = *(const half8*)(fragL + (size_t)(tn * 2 + 0) * 1024 + lane * 16);
        bl1[q] = *(const half8*)(fragL + (size_t)(tn * 2 + 1) * 1024 + lane * 16);
      }
      floatx4 ac[4];
#pragma unroll
      for (int q = 0; q < 4; ++q) ac[q] = (floatx4){0.f, 0.f, 0.f, 0.f};
#pragma unroll
      for (int tk = 0; tk < 5; ++tk)  // tk-major: 4 independent acc chains
#pragma unroll
        for (int q = 0; q < 4; ++q)
          ac[q] = __builtin_amdgcn_mfma_f32_16x16x32_f16(afrag[tk], wreg[U][q][tk], ac[q], 0, 0, 0);
#pragma unroll
      for (int q = 0; q < 4; ++q)
        ac[q] = __builtin_amdgcn_mfma_f32_16x16x32_f16(afrag[5], bl0[q], ac[q], 0, 0, 0);
#pragma unroll
      for (int q = 0; q < 4; ++q)
        ac[q] = __builtin_amdgcn_mfma_f32_16x16x32_f16(afrag[6], bl1[q], ac[q], 0, 0, 0);
#pragma unroll
      for (int q = 0; q < 4; ++q)
        ac[q] = __builtin_amdgcn_mfma_f32_16x16x32_f16(afrag[7], bg[q], ac[q], 0, 0, 0);

      floatx2 cw[4];
#pragma unroll
      for (int q = 0; q < 4; ++q) cw[q] = comboL[(q * 16 + Ug) * 16 + m15];
#pragma unroll
      for (int r = 0; r < 4; ++r) {
        float pi = ac[0][r] + xv[r] * cw[0][0] + cw[0][1];
        float pf = ac[1][r] + xv[r] * cw[1][0] + cw[1][1];
        float pg = ac[2][r] + xv[r] * cw[2][0] + cw[2][1];
        float po = ac[3][r] + xv[r] * cw[3][0] + cw[3][1];
        float cn = sigf(pf) * cst[U][r] + sigf(pi) * tanhf_(pg);
        cst[U][r] = cn;
        float hn = sigf(po) * tanhf_(cn);
        if (lane < 16) {  // only batches m=r (rows 0..3) are real
          int u = Ug * 16 + lane;
          int byte = (r * 512 + u * 2) ^ (r << 4);
          *(f16*)(hbuf + byte) = (f16)hn;
        }
      }
    }
    __syncthreads();  // B2: h^{s+1} complete

    // ---- 5. y-phase (wave 0): y = h^{s+1} @ W_out + b; next x ----
    if (wv == 0) {
      const int b = hi4, seg = m15;
      int a0 = (b * 512 + seg * 32) ^ (b << 4);
      int a1 = (b * 512 + seg * 32 + 16) ^ (b << 4);
      half8 h0 = *(const half8*)(hbuf + a0);
      half8 h1 = *(const half8*)(hbuf + a1);
      float sum = 0.f;
#pragma unroll
      for (int j = 0; j < 8; ++j)
        sum += (float)h0[j] * woutL[seg * 16 + j] + (float)h1[j] * woutL[seg * 16 + 8 + j];
      sum += __shfl_xor(sum, 1);
      sum += __shfl_xor(sum, 2);
      sum += __shfl_xor(sum, 4);
      sum += __shfl_xor(sum, 8);
      const float y = sum + bout;
      float xn;
      if (s < GLEN) {  // next x comes from prefix (clipped at 31)
        int idx = (s + 1 > GLEN - 1) ? (GLEN - 1) : (s + 1);
        float src = (idx < 16) ? pl0 : pl1;
        xn = __shfl(src, b * 16 + (idx & 15));
      } else {
        xn = y;
      }
      if (seg == 0) {
        if (s >= GLEN) out[(bbase + b) * SEQ + s] = y;
        xcur[b] = xn;
      }
    }
  }
}

extern "C" void kernel_launch(void* const* d_in, const int* in_sizes, int n_in,
                              void* d_out, int out_size, void* d_ws, size_t ws_size,
                              hipStream_t stream) {
  const float* prefix = (const float*)d_in[0];
  const float* W_ih   = (const float*)d_in[1];
  const float* W_hh   = (const float*)d_in[2];
  const float* b_ih   = (const float*)d_in[3];
  const float* b_hh   = (const float*)d_in[4];
  const float* W_out  = (const float*)d_in[5];
  const float* b_out  = (const float*)d_in[6];
  float* out = (float*)d_out;
  char* ws = (char*)d_ws;

  lstm_prep<<<dim3(129), dim3(256), 0, stream>>>(W_ih, W_hh, b_ih, b_hh, ws);
  lstm_main<<<dim3(NB), dim3(NT), 0, stream>>>(prefix, W_out, b_out, ws, out);
}

// Round 9
// 466.111 us; speedup vs baseline: 3.8994x; 1.5123x over previous
//
#include <hip/hip_runtime.h>

// LSTM rollout B=1024,S=128,H=256,glen=32. 256 blocks x 512 thr (8 waves),
// 1 block/CU, 4 batches/block, zero inter-block comm. W_hh fp16 fragments:
// tk0-3 in VGPRs (128/lane), tk4-5 in LDS (128KB), tk6-7 streamed from L2.
// Replicated-row MFMA: A rows m hold h[batch m&3], so C reg r = batch r on
// every lane -> per-lane batch select via cndmask, full-wave nonlinearity.
// (6th resubmission of round-3 source: rounds 3-8 all failed on infra.)

#define SEQ 128
#define HID 256
#define GLEN 32
#define NB  256
#define NT  512

typedef _Float16 f16;
typedef _Float16 half8 __attribute__((ext_vector_type(8)));
typedef float floatx4 __attribute__((ext_vector_type(4)));
typedef float floatx2 __attribute__((ext_vector_type(2)));

#define OFF_REG   0u
#define OFF_LDSF  (256u << 10)
#define OFF_L2F   (384u << 10)
#define OFF_COMBO (512u << 10)

__device__ __forceinline__ float sigf(float x) {
  return __builtin_amdgcn_rcpf(1.0f + __builtin_amdgcn_exp2f(-1.44269504088896341f * x));
}
__device__ __forceinline__ float tanhf_(float x) {
  float e = __builtin_amdgcn_exp2f(2.88539008177792681f * x);
  return 1.0f - 2.0f * __builtin_amdgcn_rcpf(e + 1.0f);
}
// reduce over the 16-lane DPP row via rotate-add; every lane ends with the row sum
#define RORADD(v, C) { int _t = __builtin_amdgcn_update_dpp(0, __float_as_int(v), (C), 0xF, 0xF, true); (v) += __int_as_float(_t); }

// ---------------- prep: W_hh fp32 -> fp16 MFMA B-fragments ----------------
__global__ void lstm_prep(const float* __restrict__ W_ih, const float* __restrict__ W_hh,
                          const float* __restrict__ b_ih, const float* __restrict__ b_hh,
                          char* __restrict__ ws) {
  const int blk = blockIdx.x, tid = threadIdx.x;
  if (blk < 128) {
    const int gid = blk * 256 + tid;
    const int F = gid >> 6, lane = gid & 63;
    int tn, tk; unsigned dst;
    if (F < 256) {          // reg frags: F = wv*32 + U*16 + q*4 + tk
      int wv = F >> 5, U = (F >> 4) & 1, q = (F >> 2) & 3; tk = F & 3;
      tn = q * 16 + U * 8 + wv; dst = OFF_REG + (unsigned)F * 1024;
    } else if (F < 384) {   // LDS frags: tk 4,5
      int F2 = F - 256; tn = F2 >> 1; tk = 4 + (F2 & 1); dst = OFF_LDSF + (unsigned)F2 * 1024;
    } else {                // L2-streamed frags: tk 6,7
      int F3 = F - 384; tn = F3 >> 1; tk = 6 + (F3 & 1); dst = OFF_L2F + (unsigned)F3 * 1024;
    }
    const int row = tn * 16 + (lane & 15);
    const int k0 = tk * 32 + (lane >> 4) * 8;
    const float* src = W_hh + row * HID + k0;
    half8 hv;
#pragma unroll
    for (int j = 0; j < 8; ++j) hv[j] = (f16)src[j];
    *(half8*)(ws + dst + lane * 16) = hv;
  } else {
    for (int r = tid; r < 4 * HID; r += 256) {
      floatx2 cw; cw[0] = W_ih[r]; cw[1] = b_ih[r] + b_hh[r];
      *(floatx2*)(ws + OFF_COMBO + (unsigned)r * 8) = cw;
    }
  }
}

// ---------------- main ----------------------------------------------------
__global__ __launch_bounds__(NT, 2)
void lstm_main(const float* __restrict__ prefix, const float* __restrict__ W_out,
               const float* __restrict__ b_out, const char* __restrict__ ws,
               float* __restrict__ out) {
  __shared__ __align__(16) char fragL[131072];   // tk4,5 fragments
  __shared__ __align__(16) char hbuf[2048];      // h fp16 [4 b][256 u], ^(b<<5)
  __shared__ __align__(16) floatx2 comboL[1024]; // per-row {W_ih, b_ih+b_hh}
  __shared__ float woutL[HID];
  __shared__ float pwarm[4][32];
  __shared__ float ypart[4][8];
  __shared__ float xfin[4];

  const int tid = threadIdx.x;
  const int lane = tid & 63;
  const int wv = tid >> 6;       // 0..7
  const int m15 = lane & 15;
  const int hi4 = lane >> 4;     // 0..3 = owned batch
  const int bbase = blockIdx.x * 4;

  for (int i = tid; i < 8192; i += NT)
    *(int4*)(fragL + i * 16) = *(const int4*)(ws + OFF_LDSF + i * 16);
  for (int i = tid; i < 1024; i += NT)
    comboL[i] = *(const floatx2*)(ws + OFF_COMBO + i * 8);
  if (tid < HID) woutL[tid] = W_out[tid];
  if (tid < 128) {
    int b = tid >> 5, t = tid & 31;
    float v = prefix[(bbase + b) * SEQ + t];
    pwarm[b][t] = v;
    out[(bbase + b) * SEQ + t] = v;   // prefix part of output
  }
  if (tid < 4) xfin[tid] = prefix[(bbase + tid) * SEQ];
  if (tid < 128) { int4 z = {0, 0, 0, 0}; *(int4*)(hbuf + tid * 16) = z; }
  const float bout = b_out[0];

  half8 wreg[2][4][4];   // [U][q][tk0-3]
  {
    const char* rb = ws + OFF_REG + (unsigned)wv * 32768 + (unsigned)lane * 16;
#pragma unroll
    for (int U = 0; U < 2; ++U)
#pragma unroll
      for (int q = 0; q < 4; ++q)
#pragma unroll
        for (int tk = 0; tk < 4; ++tk)
          wreg[U][q][tk] = *(const half8*)(rb + (unsigned)((U * 16 + q * 4 + tk) * 1024));
  }
  float cst[2] = {0.f, 0.f};
  const int bb = m15 & 3;
  const bool c1 = (hi4 == 1), c2 = (hi4 == 2), c3 = (hi4 == 3);

  __syncthreads();

#pragma unroll 1
  for (int s = 0; s < SEQ; ++s) {
    // A-fragments of h^s (rows replicated: row m <- batch m&3)
    half8 afrag[8];
#pragma unroll
    for (int tk = 0; tk < 8; ++tk)
      afrag[tk] = *(const half8*)(hbuf + ((bb * 512 + tk * 64 + hi4 * 16) ^ (bb << 5)));
    // U=0 L2-streamed frags issued across the barrier (latency cover)
    half8 bgA[4][2];
    {
      const int Ug = wv;
#pragma unroll
      for (int q = 0; q < 4; ++q) {
        const char* p = ws + OFF_L2F + (unsigned)((q * 16 + Ug) * 2) * 1024 + (unsigned)lane * 16;
        bgA[q][0] = *(const half8*)p;
        bgA[q][1] = *(const half8*)(p + 1024);
      }
    }
    __syncthreads();   // B1: afrag reads done -> hbuf/xfin writable
    const float xv = xfin[hi4];
    float py = 0.f;

#pragma unroll
    for (int U = 0; U < 2; ++U) {
      const int Ug = U * 8 + wv;
      half8 bg[4][2];
      if (U == 0) {
#pragma unroll
        for (int q = 0; q < 4; ++q) { bg[q][0] = bgA[q][0]; bg[q][1] = bgA[q][1]; }
      } else {
#pragma unroll
        for (int q = 0; q < 4; ++q) {
          const char* p = ws + OFF_L2F + (unsigned)((q * 16 + Ug) * 2) * 1024 + (unsigned)lane * 16;
          bg[q][0] = *(const half8*)p;
          bg[q][1] = *(const half8*)(p + 1024);
        }
      }
      floatx2 cw[4];
#pragma unroll
      for (int q = 0; q < 4; ++q) cw[q] = comboL[(q * 16 + Ug) * 16 + m15];
      floatx4 ac[4];
#pragma unroll
      for (int q = 0; q < 4; ++q) ac[q] = (floatx4){0.f, 0.f, 0.f, 0.f};
      // LDS frags with 1-q lookahead
      half8 nb0, nb1;
      {
        const char* p = fragL + (unsigned)((0 * 16 + Ug) * 2) * 1024 + (unsigned)lane * 16;
        nb0 = *(const half8*)p; nb1 = *(const half8*)(p + 1024);
      }
#pragma unroll
      for (int q = 0; q < 4; ++q) {
        half8 b0 = nb0, b1 = nb1;
        if (q < 3) {
          const char* p = fragL + (unsigned)(((q + 1) * 16 + Ug) * 2) * 1024 + (unsigned)lane * 16;
          nb0 = *(const half8*)p; nb1 = *(const half8*)(p + 1024);
        }
        ac[q] = __builtin_amdgcn_mfma_f32_16x16x32_f16(afrag[0], wreg[U][q][0], ac[q], 0, 0, 0);
        ac[q] = __builtin_amdgcn_mfma_f32_16x16x32_f16(afrag[1], wreg[U][q][1], ac[q], 0, 0, 0);
        ac[q] = __builtin_amdgcn_mfma_f32_16x16x32_f16(afrag[2], wreg[U][q][2], ac[q], 0, 0, 0);
        ac[q] = __builtin_amdgcn_mfma_f32_16x16x32_f16(afrag[3], wreg[U][q][3], ac[q], 0, 0, 0);
        ac[q] = __builtin_amdgcn_mfma_f32_16x16x32_f16(afrag[4], b0, ac[q], 0, 0, 0);
        ac[q] = __builtin_amdgcn_mfma_f32_16x16x32_f16(afrag[5], b1, ac[q], 0, 0, 0);
        ac[q] = __builtin_amdgcn_mfma_f32_16x16x32_f16(afrag[6], bg[q][0], ac[q], 0, 0, 0);
        ac[q] = __builtin_amdgcn_mfma_f32_16x16x32_f16(afrag[7], bg[q][1], ac[q], 0, 0, 0);
      }
      // row r of C = batch r (replicated A) -> select own batch hi4, in-lane
      float g[4];
#pragma unroll
      for (int q = 0; q < 4; ++q) {
        float v = ac[q][0];
        v = c1 ? ac[q][1] : v;
        v = c2 ? ac[q][2] : v;
        v = c3 ? ac[q][3] : v;
        g[q] = v;
      }
      float pi = g[0] + __builtin_fmaf(xv, cw[0][0], cw[0][1]);
      float pf = g[1] + __builtin_fmaf(xv, cw[1][0], cw[1][1]);
      float pg = g[2] + __builtin_fmaf(xv, cw[2][0], cw[2][1]);
      float po = g[3] + __builtin_fmaf(xv, cw[3][0], cw[3][1]);
      float cn = __builtin_fmaf(sigf(pf), cst[U], sigf(pi) * tanhf_(pg));
      cst[U] = cn;
      float hn = sigf(po) * tanhf_(cn);
      const int u = Ug * 16 + m15;
      *(f16*)(hbuf + ((hi4 * 512 + u * 2) ^ (hi4 << 5))) = (f16)hn;
      if (s >= GLEN) py = __builtin_fmaf(hn, woutL[u], py);
    }

    if (s >= GLEN) {   // y partials: reduce over the 16-lane row (units)
      RORADD(py, 0x121); RORADD(py, 0x122); RORADD(py, 0x124); RORADD(py, 0x128);
      if (m15 == 0) ypart[hi4][wv] = py;
    }
    __syncthreads();   // B2: h^{s+1} + ypart complete
    if (wv == 0) {
      if (s >= GLEN) {
        float v = ((const float*)ypart)[lane & 31];   // [b=L>>3][wv=L&7]
        v += __shfl_xor(v, 1);
        v += __shfl_xor(v, 2);
        v += __shfl_xor(v, 4);
        if (lane < 32 && (lane & 7) == 0) {
          const int b = lane >> 3;
          const float y = v + bout;
          out[(bbase + b) * SEQ + s] = y;
          xfin[b] = y;               // autoregressive feed
        }
      } else {
        if (lane < 4) {
          const int idx = (s + 1 < GLEN) ? (s + 1) : (GLEN - 1);
          xfin[lane] = pwarm[lane][idx];
        }
      }
    }
  }
}

extern "C" void kernel_launch(void* const* d_in, const int* in_sizes, int n_in,
                              void* d_out, int out_size, void* d_ws, size_t ws_size,
                              hipStream_t stream) {
  const float* prefix = (const float*)d_in[0];
  const float* W_ih   = (const float*)d_in[1];
  const float* W_hh   = (const float*)d_in[2];
  const float* b_ih   = (const float*)d_in[3];
  const float* b_hh   = (const float*)d_in[4];
  const float* W_out  = (const float*)d_in[5];
  const float* b_out  = (const float*)d_in[6];
  float* out = (float*)d_out;
  char* ws = (char*)d_ws;

  lstm_prep<<<dim3(129), dim3(256), 0, stream>>>(W_ih, W_hh, b_ih, b_hh, ws);
  lstm_main<<<dim3(NB), dim3(NT), 0, stream>>>(prefix, W_out, b_out, ws, out);
}